// Round 10
// baseline (163.703 us; speedup 1.0000x reference)
//
#include <hip/hip_runtime.h>
#include <hip/hip_bf16.h>

// Problem: B=4, L=2048, D_MODEL=1024, H=16, D_QKV=64.
// Reference einsum 'bhlk,blhd->blhd' contracts k over logits only; softmax sums to 1,
// so attention output == v and the net reduces to:
//   out = x @ Wc + fc_b,  Wc[m][j] = sum_{hd} w_v[h][m][d] * fc_w[j][hd]
// Lesson from r2-r9 trajectory: prep wants MASSIVE grids (r2's 8192/4096-block streaming
// kernels + 64-block 128x128 gather-GEMM on packed bf16 = ~22us aggregate; every
// consolidation since regressed it). Revert to r2 pieces verbatim + r7 final_gemm.

typedef __attribute__((ext_vector_type(8))) short bf16x8;
typedef __attribute__((ext_vector_type(4))) float f32x4;
typedef __attribute__((ext_vector_type(4))) unsigned short u16x4;

__device__ __forceinline__ f32x4 mfma16(bf16x8 a, bf16x8 b, f32x4 c) {
  return __builtin_amdgcn_mfma_f32_16x16x32_bf16(a, b, c, 0, 0, 0);
}

// fp32 -> bf16 bits, round-to-nearest-even
__device__ __forceinline__ unsigned short f2b(float f) {
  unsigned int u = __builtin_bit_cast(unsigned int, f);
  return (unsigned short)((u + 0x7fffu + ((u >> 16) & 1u)) >> 16);
}

__device__ __forceinline__ u16x4 cvt4(float4 a) {
  u16x4 r;
  r[0] = f2b(a.x); r[1] = f2b(a.y); r[2] = f2b(a.z); r[3] = f2b(a.w);
  return r;
}

// async global->LDS, 16 B per lane (m97 pattern; LDS dest = wave-uniform base + lane*16)
__device__ __forceinline__ void gld_lds16(const void* g, void* l) {
  __builtin_amdgcn_global_load_lds((const __attribute__((address_space(1))) unsigned int*)g,
                                   (__attribute__((address_space(3))) unsigned int*)l, 16, 0, 0);
}

// x fp32 -> bf16, 4 elems/thread, 8192 blocks (r2 verbatim — 32 blocks/CU latency hiding)
__global__ void cast4(const float* __restrict__ in, unsigned short* __restrict__ out) {
  int i = (blockIdx.x * 256 + threadIdx.x) * 4;
  float4 v = *reinterpret_cast<const float4*>(in + i);
  *reinterpret_cast<u16x4*>(out + i) = cvt4(v);
}

// 2048 blocks: bid<1024 cast fcw->bf16; else pack wvp[m][h*64+d] = wv[h][m][d] (bf16).
__global__ void castpack(const float* __restrict__ fcw, const float* __restrict__ wv,
                         unsigned short* __restrict__ fcwb, unsigned short* __restrict__ wvp) {
  int bid = blockIdx.x, t = threadIdx.x;
  if (bid < 1024) {
    int i = (bid * 256 + t) * 4;
    *reinterpret_cast<u16x4*>(fcwb + i) = cvt4(*reinterpret_cast<const float4*>(fcw + i));
  } else {
    int tid = (bid - 1024) * 256 + t;       // 0 .. 262143
    int m = tid >> 8, hd4 = (tid & 255) * 4;
    int h = hd4 >> 6, d = hd4 & 63;
    float4 v = *reinterpret_cast<const float4*>(wv + (h << 16) + (m << 6) + d);
    *reinterpret_cast<u16x4*>(wvp + m * 1024 + hd4) = cvt4(v);
  }
}

// wcT[j][m] = sum_k fcwb[j][k] * wvp[m][k].  1024x1024, bf16 out. (r2 verbatim: 64 blocks,
// 128x128 tile, direct per-lane 16B gather from packed bf16 rows — 8 loads feed 16 MFMAs.)
__global__ __launch_bounds__(256) void wc_gemm(const unsigned short* __restrict__ fcwb,
                                               const unsigned short* __restrict__ wvp,
                                               unsigned short* __restrict__ wcT) {
  int wid = threadIdx.x >> 6;
  int lane = threadIdx.x & 63, l16 = lane & 15, quad = lane >> 4;
  int row0 = blockIdx.y * 128 + (wid >> 1) * 64;   // j
  int col0 = blockIdx.x * 128 + (wid & 1) * 64;    // m
  f32x4 acc[16];
#pragma unroll
  for (int i = 0; i < 16; i++) acc[i] = (f32x4){0.f, 0.f, 0.f, 0.f};

  const unsigned short* Ab = fcwb + (row0 + l16) * 1024 + quad * 8;
  const unsigned short* Bb = wvp + (col0 + l16) * 1024 + quad * 8;
  for (int k0 = 0; k0 < 1024; k0 += 32) {
    bf16x8 af[4], bfr[4];
#pragma unroll
    for (int tt = 0; tt < 4; tt++) {
      af[tt]  = *reinterpret_cast<const bf16x8*>(Ab + tt * 16 * 1024 + k0);
      bfr[tt] = *reinterpret_cast<const bf16x8*>(Bb + tt * 16 * 1024 + k0);
    }
#pragma unroll
    for (int rt = 0; rt < 4; rt++)
#pragma unroll
      for (int ct = 0; ct < 4; ct++)
        acc[rt * 4 + ct] = mfma16(af[rt], bfr[ct], acc[rt * 4 + ct]);
  }
#pragma unroll
  for (int rt = 0; rt < 4; rt++)
#pragma unroll
    for (int ct = 0; ct < 4; ct++) {
      int j = row0 + rt * 16 + quad * 4;
      int m = col0 + ct * 16 + l16;
      f32x4 a = acc[rt * 4 + ct];
#pragma unroll
      for (int r = 0; r < 4; r++) wcT[(j + r) * 1024 + m] = f2b(a[r]);
    }
}

// out[i][j] = sum_m xb[i][m]*wcT[j][m] + fcb[j].  M=8192,N=1024,K=1024.  (r7 verbatim.)
// 128x64 tile, BK=64 (two 32-k slabs), 1024 blocks N-fastest, LDS 24KB, 4 blocks/CU.
__global__ __launch_bounds__(256, 4) void final_gemm(const unsigned short* __restrict__ xb,
                                                     const unsigned short* __restrict__ wcT,
                                                     const float* __restrict__ fcb,
                                                     float* __restrict__ out) {
  __shared__ __align__(16) unsigned short As[2 * 128 * 32];  // 16 KB  [slab][row][32]
  __shared__ __align__(16) unsigned short Bs[2 * 64 * 32];   //  8 KB
  int t = threadIdx.x, wid = t >> 6, lane = t & 63, l16 = lane & 15, quad = lane >> 4;
  int wr = wid >> 1, wc = wid & 1;
  int row0 = (blockIdx.x >> 4) * 128;   // M tile (64)
  int col0 = (blockIdx.x & 15) * 64;    // N tile (16) — fastest: B stays L2-hot

  int w4 = wid * 4, w2 = wid * 2;
  const unsigned short* Ap[4];
  const unsigned short* Bp[2];
#pragma unroll
  for (int j = 0; j < 4; j++) {
    int blk = w4 + j, s = blk >> 3;
    int row = (blk & 7) * 16 + (lane >> 2), kq = lane & 3;
    Ap[j] = xb + (row0 + row) * 1024 + s * 32 + kq * 8;
  }
#pragma unroll
  for (int j = 0; j < 2; j++) {
    int blk = w2 + j, s = blk >> 2;
    int row = (blk & 3) * 16 + (lane >> 2), kq = lane & 3;
    Bp[j] = wcT + (col0 + row) * 1024 + s * 32 + kq * 8;
  }

  f32x4 acc[4][2];
#pragma unroll
  for (int rt = 0; rt < 4; rt++)
#pragma unroll
    for (int ct = 0; ct < 2; ct++) acc[rt][ct] = (f32x4){0.f, 0.f, 0.f, 0.f};

  for (int k0 = 0; k0 < 1024; k0 += 64) {
    __syncthreads();
#pragma unroll
    for (int j = 0; j < 4; j++) gld_lds16(Ap[j] + k0, &As[(w4 + j) * 512 + lane * 8]);
#pragma unroll
    for (int j = 0; j < 2; j++) gld_lds16(Bp[j] + k0, &Bs[(w2 + j) * 512 + lane * 8]);
    __syncthreads();
#pragma unroll
    for (int s = 0; s < 2; s++) {
      bf16x8 af[4], bfr[2];
#pragma unroll
      for (int rt = 0; rt < 4; rt++)
        af[rt] = *reinterpret_cast<const bf16x8*>(&As[s * 4096 + (wr * 64 + rt * 16 + l16) * 32 + quad * 8]);
#pragma unroll
      for (int ct = 0; ct < 2; ct++)
        bfr[ct] = *reinterpret_cast<const bf16x8*>(&Bs[s * 2048 + (wc * 32 + ct * 16 + l16) * 32 + quad * 8]);
#pragma unroll
      for (int rt = 0; rt < 4; rt++)
#pragma unroll
        for (int ct = 0; ct < 2; ct++)
          acc[rt][ct] = mfma16(af[rt], bfr[ct], acc[rt][ct]);
    }
  }

#pragma unroll
  for (int ct = 0; ct < 2; ct++) {
    int j = col0 + wc * 32 + ct * 16 + l16;
    float bias = fcb[j];
#pragma unroll
    for (int rt = 0; rt < 4; rt++) {
      int i0 = row0 + wr * 64 + rt * 16 + quad * 4;
      f32x4 a = acc[rt][ct];
#pragma unroll
      for (int r = 0; r < 4; r++) out[(i0 + r) * 1024 + j] = a[r] + bias;
    }
  }
}

extern "C" void kernel_launch(void* const* d_in, const int* in_sizes, int n_in,
                              void* d_out, int out_size, void* d_ws, size_t ws_size,
                              hipStream_t stream) {
  const float* x   = (const float*)d_in[0];
  // d_in[1] mask, d_in[2] w_q, d_in[3] w_k: dead per reference semantics
  const float* wv  = (const float*)d_in[4];
  const float* fcw = (const float*)d_in[5];
  const float* fcb = (const float*)d_in[6];
  float* out = (float*)d_out;

  char* ws = (char*)d_ws;
  unsigned short* xb   = (unsigned short*)(ws);              // 16 MB (8192x1024 bf16)
  unsigned short* wcT  = (unsigned short*)(ws + 16777216);   // 2 MB  (1024x1024 bf16)
  unsigned short* fcwb = (unsigned short*)(ws + 18874368);   // 2 MB
  unsigned short* wvp  = (unsigned short*)(ws + 20971520);   // 2 MB

  castpack<<<2048, 256, 0, stream>>>(fcw, wv, fcwb, wvp);
  cast4<<<8192, 256, 0, stream>>>(x, xb);
  wc_gemm<<<dim3(8, 8), 256, 0, stream>>>(fcwb, wvp, wcT);
  final_gemm<<<1024, 256, 0, stream>>>(xb, wcT, fcb, out);
}